// Round 9
// baseline (171.521 us; speedup 1.0000x reference)
//
#include <hip/hip_runtime.h>
#include <hip/hip_bf16.h>

typedef __attribute__((ext_vector_type(8)))  short bf16x8;
typedef __attribute__((ext_vector_type(16))) float f32x16;

#define TPB 512
// MFMA score error bound ~1e-4 (bf16 hi/lo split of ya, fp32 accumulate, C-add);
// 1e-3 margin gives ~10x headroom -> unflagged decisions provably match fp64.
#define SCORE_MARGIN 1e-3f
#define ERR_MARGIN   1e-3f

static __device__ __forceinline__ unsigned short bf16_rne(float v) {
    union { __hip_bfloat16 h; unsigned short u; } cv;
    cv.h = __float2bfloat16(v);
    return cv.u;
}

// ---------------------------------------------------------------------------
// Single fused kernel, mfma_f32_32x32x16_bf16 (verified R8, absmax 0.0):
// A = codewords (32 cw/tile, K = 8 dims x {hi,lo}, both k-halves read the
// same 16B -> 1 broadcast ds_read_b128/tile), B = ya (loop-invariant hi/lo),
// C = -n/2. R9 change: norms stored PRE-SCALED (-n/2, bf16-exact: n in
// {2..12}) and PERMUTED into exact C-register order per k-half h, so the C
// preload is 2 broadcast ds_read_b128 + 16 shift/and unpacks instead of
// R8's 4 ds_read_b128 of f32 — LDS pipe/tile 60->36 cyc (the measured
// per-CU floor). TPB 512 + __launch_bounds__(512,4): 16 waves/CU ceiling
// (R8 measured 21% occupancy => latency-bound).
// Output d_out (float32): [final_vals (N*8) | final_idxs (N)].
// ---------------------------------------------------------------------------
__global__ __launch_bounds__(TPB, 4) void e8p_fused(
    const float* __restrict__ X,
    const float* __restrict__ grid_part,
    const float* __restrict__ grid_part_norm,
    const int*   __restrict__ allcombo_idx,
    const int*   __restrict__ idx_map,
    float* __restrict__ out,
    int N, int G, int T)
{
    extern __shared__ __align__(16) unsigned char smem[];
    const int T32 = T * 32;
    unsigned char* ldsG = smem;                       // T32 cw x 16B bf16x8
    unsigned short* ldsN = (unsigned short*)(smem + (size_t)T32 * 16);
    // ldsN: per tile 32 bf16 = [h=0: 16 slots r][h=1: 16 slots r], value -n/2

    const int tid = threadIdx.x;

    // ---- stage codebook: g as bf16x8 (exact); -n/2 bf16 permuted to C order
    for (int c = tid; c < T32; c += TPB) {
        uint4 gv; float nv;
        if (c < G) {
            const float4 g0 = *(const float4*)(grid_part + (size_t)c * 8);
            const float4 g1 = *(const float4*)(grid_part + (size_t)c * 8 + 4);
            gv.x = (unsigned)bf16_rne(g0.x) | ((unsigned)bf16_rne(g0.y) << 16);
            gv.y = (unsigned)bf16_rne(g0.z) | ((unsigned)bf16_rne(g0.w) << 16);
            gv.z = (unsigned)bf16_rne(g1.x) | ((unsigned)bf16_rne(g1.y) << 16);
            gv.w = (unsigned)bf16_rne(g1.z) | ((unsigned)bf16_rne(g1.w) << 16);
            nv = -0.5f * grid_part_norm[c];           // in {-1..-6}: bf16-exact
        } else {
            gv.x = gv.y = gv.z = gv.w = 0u;  // pad cw: dot 0, C-slot -30000
            nv = -30000.0f;                  // (bf16 ~ -29952, never wins/sec)
        }
        *(uint4*)(ldsG + (size_t)c * 16) = gv;
        // C/D row w = (r&3) + 8*(r>>2) + 4h  ->  h = (w>>2)&1, r = (w&3)+4*(w>>3)
        const int t = c >> 5, w = c & 31;
        const int h = (w >> 2) & 1;
        const int r = (w & 3) + 4 * (w >> 3);
        ldsN[t * 32 + h * 16 + r] = bf16_rne(nv);
    }
    __syncthreads();

    const int lane = tid & 63;
    const int h    = lane >> 5;        // k-half / C-row offset 4h
    const int col  = lane & 31;        // B col = (input row, branch)
    const int wave = blockIdx.x * (TPB / 64) + (tid >> 6);

    const int li     = col >> 1;
    const int branch = col & 1;        // 0: +0.25, 1: -0.25
    const int irow   = wave * 16 + li;
    const int iload  = (irow < N) ? irow : 0;

    float x[8];
    {
        const float4 a = *(const float4*)(X + (size_t)iload * 8);
        const float4 b = *(const float4*)(X + (size_t)iload * 8 + 4);
        x[0]=a.x; x[1]=a.y; x[2]=a.z; x[3]=a.w;
        x[4]=b.x; x[5]=b.y; x[6]=b.z; x[7]=b.w;
    }

    // Branch prep (fp32 signs == fp64 signs: correctly-rounded add can't cross 0)
    float ya[8]; int neg = 0;
    const float sh = branch ? -0.25f : 0.25f;
#pragma unroll
    for (int j = 0; j < 8; ++j) {
        const float yj = x[j] + sh;
        if (yj < 0.0f) neg |= (1 << (7 - j));
        ya[j] = fabsf(yj);
    }
    int mint = neg;
    if (__popc(neg) & 1) { ya[0] = -ya[0]; mint ^= 128; }

    // B fragment (loop-invariant): h=0 -> bf16_hi(ya), h=1 -> bf16_lo residual
    bf16x8 bfrag;
#pragma unroll
    for (int j = 0; j < 8; ++j) {
        const unsigned short hi = bf16_rne(ya[j]);
        const unsigned short lo = bf16_rne(ya[j] - __uint_as_float(((unsigned)hi) << 16));
        bfrag[j] = (short)(h ? lo : hi);
    }

    float best[16], sec[16]; int q[16];
#pragma unroll
    for (int r = 0; r < 16; ++r) { best[r] = -1e30f; sec[r] = -1e30f; q[r] = 0; }

    const unsigned aoff = (unsigned)col * 16u;
    const unsigned char* nbase = (const unsigned char*)ldsN + h * 32;
    for (int t = 0; t < T; ++t) {
        const bf16x8 afrag = *(const bf16x8*)(ldsG + (size_t)t * 512 + aoff);
        // 2 broadcast b128: 16 bf16 norms in C-reg order for this h
        const uint4 n0 = *(const uint4*)(nbase + (size_t)t * 64);
        const uint4 n1 = *(const uint4*)(nbase + (size_t)t * 64 + 16);
        f32x16 cf;
        cf[0]  = __uint_as_float(n0.x << 16);
        cf[1]  = __uint_as_float(n0.x & 0xffff0000u);
        cf[2]  = __uint_as_float(n0.y << 16);
        cf[3]  = __uint_as_float(n0.y & 0xffff0000u);
        cf[4]  = __uint_as_float(n0.z << 16);
        cf[5]  = __uint_as_float(n0.z & 0xffff0000u);
        cf[6]  = __uint_as_float(n0.w << 16);
        cf[7]  = __uint_as_float(n0.w & 0xffff0000u);
        cf[8]  = __uint_as_float(n1.x << 16);
        cf[9]  = __uint_as_float(n1.x & 0xffff0000u);
        cf[10] = __uint_as_float(n1.y << 16);
        cf[11] = __uint_as_float(n1.y & 0xffff0000u);
        cf[12] = __uint_as_float(n1.z << 16);
        cf[13] = __uint_as_float(n1.z & 0xffff0000u);
        cf[14] = __uint_as_float(n1.w << 16);
        cf[15] = __uint_as_float(n1.w & 0xffff0000u);
        const f32x16 d = __builtin_amdgcn_mfma_f32_32x32x16_bf16(afrag, bfrag, cf, 0, 0, 0);
#pragma unroll
        for (int r = 0; r < 16; ++r) {
            const float s = d[r];
            const bool gt = s > best[r];              // first-max-wins per slot
            sec[r]  = __builtin_amdgcn_fmed3f(s, best[r], sec[r]);
            best[r] = fmaxf(best[r], s);
            q[r]    = gt ? t : q[r];
        }
    }

    // ---- reduce 16 slots -> 1 (lexicographic max-score, min-index; second =
    // max(secs, min(bests)) so equal-best distinct codewords flag the margin)
    float bb = best[0], ss = sec[0];
    int   ii = 32 * q[0] + 4 * h;                     // r=0 rowoff = 4h
#pragma unroll
    for (int r = 1; r < 16; ++r) {
        const int rowoff = (r & 3) + 8 * (r >> 2) + 4 * h;
        const int idx = 32 * q[r] + rowoff;
        const float br = best[r];
        ss = fmaxf(fmaxf(ss, sec[r]), fminf(bb, br));
        const bool take = (br > bb) || ((br == bb) && (idx < ii));
        bb = fmaxf(bb, br);
        ii = take ? idx : ii;
    }
    {   // butterfly across the two k-half lane groups (offset 32)
        const float ob = __shfl_xor(bb, 32, 64);
        const float os = __shfl_xor(ss, 32, 64);
        const int   oi = __shfl_xor(ii, 32, 64);
        ss = fmaxf(fmaxf(ss, os), fminf(bb, ob));
        const bool take = (ob > bb) || ((ob == bb) && (oi < ii));
        bb = fmaxf(bb, ob);
        ii = take ? oi : ii;
    }
    // pair swap: even col (plus branch) receives odd col (minus branch)
    const float bbO   = __shfl_xor(bb, 1, 64);
    const float ssO   = __shfl_xor(ss, 1, 64);
    const int   iiO   = __shfl_xor(ii, 1, 64);
    const int   mintO = __shfl_xor(mint, 1, 64);

    const bool doEpi = (h == 0) && (branch == 0) && (irow < N);
    bool close = false;
    if (doEpi) {
        const int qP = ii, qM = iiO;
        const float* gp_ = grid_part + (size_t)qP * 8;
        const float* gm_ = grid_part + (size_t)qM * 8;
        float vp[8], vm[8];
        float ep2 = 0.0f, em2 = 0.0f;
        bool coin = true;
#pragma unroll
        for (int j = 0; j < 8; ++j) {
            const float maskp = ((mint  >> (7 - j)) & 1) ? -1.0f : 1.0f;
            const float maskm = ((mintO >> (7 - j)) & 1) ? -1.0f : 1.0f;
            vp[j] = gp_[j] * maskp;
            vm[j] = gm_[j] * maskm;
            coin = coin && ((vp[j] - 0.25f) == (vm[j] + 0.25f));  // exact fp32
            const float dpj = (x[j] + 0.25f) - vp[j];
            const float dmj = (x[j] - 0.25f) - vm[j];
            ep2 = fmaf(dpj, dpj, ep2);
            em2 = fmaf(dmj, dmj, em2);
        }
        close = ((bb - ss) < SCORE_MARGIN) | ((bbO - ssO) < SCORE_MARGIN) |
                (!coin && (fabsf(ep2 - em2) < ERR_MARGIN));
        if (!close) {
            // Coincident -> fp64 ref has pe==me bit-exactly -> which=false.
            const bool which = coin ? false : (ep2 < em2);
            const int rowp = idx_map[mint];
            const int rowm = idx_map[mintO];
            const int pi = allcombo_idx[(size_t)rowp * G + qP];
            const int mi = allcombo_idx[(size_t)rowm * G + qM];
            const float idxval = which ? (float)pi : (float)(mi - 32768);
            float* vout = out + (size_t)irow * 8;
#pragma unroll
            for (int j = 0; j < 8; ++j)
                vout[j] = which ? (vp[j] - 0.25f) : (vm[j] + 0.25f);
            out[(size_t)N * 8 + irow] = idxval;
        }
    }

    // ---- inline fp64 fixup for flagged rows (R2-verified arithmetic) ----
    unsigned long long mb = __ballot(doEpi && close);
    while (mb) {
        const int b = (int)__ffsll(mb) - 1;   // flagged lane: h=0, even col
        mb &= (mb - 1);
        const int liF = b >> 1;
        const int iF  = wave * 16 + liF;
        float xf[8];
#pragma unroll
        for (int j = 0; j < 8; ++j) xf[j] = __shfl(x[j], b, 64);

        double yapF[8], yamF[8];
        int negp = 0, negm = 0;
#pragma unroll
        for (int j = 0; j < 8; ++j) {
            const double xd = (double)xf[j];
            const double ypd = xd + 0.25;
            const double ymd = xd - 0.25;
            if (ypd < 0.0) negp |= (1 << (7 - j));
            if (ymd < 0.0) negm |= (1 << (7 - j));
            yapF[j] = fabs(ypd);
            yamF[j] = fabs(ymd);
        }
        int mintpF = negp, mintmF = negm;
        if (__popc(negp) & 1) { yapF[0] = -yapF[0]; mintpF ^= 128; }
        if (__popc(negm) & 1) { yamF[0] = -yamF[0]; mintmF ^= 128; }

        double bestpF = -1e300, bestmF = -1e300;
        int qpF = 0x7fffffff, qmF = 0x7fffffff;
        for (int j = lane; j < G; j += 64) {
            const float4 g0 = *(const float4*)(grid_part + (size_t)j * 8);
            const float4 g1 = *(const float4*)(grid_part + (size_t)j * 8 + 4);
            const double n = (double)grid_part_norm[j];
            const double t0 = (double)g0.x, t1 = (double)g0.y,
                         t2 = (double)g0.z, t3 = (double)g0.w,
                         t4 = (double)g1.x, t5 = (double)g1.y,
                         t6 = (double)g1.z, t7 = (double)g1.w;
            double dp, dm;
            dp = yapF[0] * t0;           dm = yamF[0] * t0;
            dp = fma(yapF[1], t1, dp);   dm = fma(yamF[1], t1, dm);
            dp = fma(yapF[2], t2, dp);   dm = fma(yamF[2], t2, dm);
            dp = fma(yapF[3], t3, dp);   dm = fma(yamF[3], t3, dm);
            dp = fma(yapF[4], t4, dp);   dm = fma(yamF[4], t4, dm);
            dp = fma(yapF[5], t5, dp);   dm = fma(yamF[5], t5, dm);
            dp = fma(yapF[6], t6, dp);   dm = fma(yamF[6], t6, dm);
            dp = fma(yapF[7], t7, dp);   dm = fma(yamF[7], t7, dm);
            const double sp = 2.0 * dp - n;
            const double sm = 2.0 * dm - n;
            if (sp > bestpF) { bestpF = sp; qpF = j; }
            if (sm > bestmF) { bestmF = sm; qmF = j; }
        }
#pragma unroll
        for (int off = 32; off > 0; off >>= 1) {
            double ob = __shfl_xor(bestpF, off, 64);
            int    oq = __shfl_xor(qpF, off, 64);
            if (ob > bestpF || (ob == bestpF && oq < qpF)) { bestpF = ob; qpF = oq; }
            ob = __shfl_xor(bestmF, off, 64);
            oq = __shfl_xor(qmF, off, 64);
            if (ob > bestmF || (ob == bestmF && oq < qmF)) { bestmF = ob; qmF = oq; }
        }
        if (lane == 0) {
            const float* gp_ = grid_part + (size_t)qpF * 8;
            const float* gm_ = grid_part + (size_t)qmF * 8;
            double vp[8], vm[8];
            double ep2 = 0.0, em2 = 0.0;
#pragma unroll
            for (int j = 0; j < 8; ++j) {
                const double maskp = ((mintpF >> (7 - j)) & 1) ? -1.0 : 1.0;
                const double maskm = ((mintmF >> (7 - j)) & 1) ? -1.0 : 1.0;
                vp[j] = (double)gp_[j] * maskp;
                vm[j] = (double)gm_[j] * maskm;
                const double xd = (double)xf[j];
                const double dpj = (xd + 0.25) - vp[j];
                const double dmj = (xd - 0.25) - vm[j];
                ep2 += dpj * dpj;
                em2 += dmj * dmj;
            }
            const double ep = sqrt(ep2), em = sqrt(em2);
            const bool which = ep < em;
            const int rowp = idx_map[mintpF];
            const int rowm = idx_map[mintmF];
            const int pi = allcombo_idx[(size_t)rowp * G + qpF];
            const int mi = allcombo_idx[(size_t)rowm * G + qmF];
            const float idxval = which ? (float)pi : (float)(mi - 32768);
            float* vout = out + (size_t)iF * 8;
#pragma unroll
            for (int j = 0; j < 8; ++j) {
                const double v = which ? (vp[j] - 0.25) : (vm[j] + 0.25);
                vout[j] = (float)v;
            }
            out[(size_t)N * 8 + iF] = idxval;
        }
    }
}

extern "C" void kernel_launch(void* const* d_in, const int* in_sizes, int n_in,
                              void* d_out, int out_size, void* d_ws, size_t ws_size,
                              hipStream_t stream) {
    const float* X    = (const float*)d_in[0];
    const float* gp   = (const float*)d_in[1];
    const float* gn   = (const float*)d_in[2];
    const int*   aci  = (const int*)d_in[3];
    const int*   imap = (const int*)d_in[4];
    // d_in[5] (int_map) and d_in[6] (grid_idx_map) are folded analytically.

    const int N = in_sizes[0] / 8;
    const int G = in_sizes[1] / 8;
    const int T = (G + 31) / 32;                 // tiles of 32 codewords
    const int blocks = (N + 127) / 128;          // 8 waves x 16 rows per block
    const size_t shmem = (size_t)T * 512 + (size_t)T * 64;  // ~24.8KB

    hipLaunchKernelGGL(e8p_fused, dim3(blocks), dim3(TPB), shmem, stream,
                       X, gp, gn, aci, imap, (float*)d_out, N, G, T);
}